// Round 1
// baseline (467.693 us; speedup 1.0000x reference)
//
#include <hip/hip_runtime.h>
#include <math.h>

#define PROJ 8192
#define CDIM 512
#define HWPOS 196
#define NBATCH 32

// ---------------------------------------------------------------------------
// Kernel 1: extract (h, s) from the dense sketch matrices.
// Each row of M [512 x 8192] has exactly one nonzero (+-1) at column h[c].
// Grid: (512 rows, 2 matrices), block 256.
// ---------------------------------------------------------------------------
__global__ __launch_bounds__(256) void extract_kernel(
    const float* __restrict__ M1, const float* __restrict__ M2,
    int* __restrict__ h1, float* __restrict__ s1,
    int* __restrict__ h2, float* __restrict__ s2)
{
    const int row = blockIdx.x;
    const float* M = blockIdx.y ? M2 : M1;
    int*   h = blockIdx.y ? h2 : h1;
    float* s = blockIdx.y ? s2 : s1;
    const float* mrow = M + (size_t)row * PROJ;

    if (threadIdx.x == 0) { h[row] = 0; s[row] = 0.0f; }
    __syncthreads();

    // 256 threads x 8 float4 = 8192 elements
    for (int i = threadIdx.x * 4; i < PROJ; i += 256 * 4) {
        float4 v = *(const float4*)(mrow + i);
        if (v.x != 0.0f) { h[row] = i + 0; s[row] = v.x; }
        if (v.y != 0.0f) { h[row] = i + 1; s[row] = v.y; }
        if (v.z != 0.0f) { h[row] = i + 2; s[row] = v.z; }
        if (v.w != 0.0f) { h[row] = i + 3; s[row] = v.w; }
    }
}

// ---------------------------------------------------------------------------
// Kernel 2: batched Gram  G[b] = X_b^T X_b,  X_b = x[b] reshaped [196 x 512].
// Tile 128x128 of G per workgroup, 256 threads, 8x8 per-thread register block.
// Grid: (4, 4, 32).
// ---------------------------------------------------------------------------
__global__ __launch_bounds__(256) void gram_kernel(
    const float* __restrict__ x, float* __restrict__ G)
{
    const int bat = blockIdx.z;
    const int bi  = blockIdx.x;   // row tile of G (c1 / 128)
    const int bj  = blockIdx.y;   // col tile of G (c2 / 128)

    __shared__ __align__(16) float As[8][128];
    __shared__ __align__(16) float Bs[8][128];

    const float* Xb = x + (size_t)bat * HWPOS * CDIM;

    float acc[8][8];
#pragma unroll
    for (int i = 0; i < 8; ++i)
#pragma unroll
        for (int j = 0; j < 8; ++j) acc[i][j] = 0.0f;

    const int tid  = threadIdx.x;
    const int ti   = tid >> 4;        // 0..15 (G sub-row group)
    const int tj   = tid & 15;        // 0..15 (G sub-col group)
    const int lrow = tid >> 5;        // 0..7  (staging row)
    const int lcol = (tid & 31) * 4;  // 0..124 (staging col, float4)

    for (int k0 = 0; k0 < HWPOS; k0 += 8) {
        const int krow = k0 + lrow;
        float4 a4 = make_float4(0.f, 0.f, 0.f, 0.f);
        float4 b4 = make_float4(0.f, 0.f, 0.f, 0.f);
        if (krow < HWPOS) {
            const float* xr = Xb + (size_t)krow * CDIM;
            a4 = *(const float4*)(xr + bi * 128 + lcol);
            b4 = *(const float4*)(xr + bj * 128 + lcol);
        }
        *(float4*)&As[lrow][lcol] = a4;
        *(float4*)&Bs[lrow][lcol] = b4;
        __syncthreads();

#pragma unroll
        for (int kk = 0; kk < 8; ++kk) {
            float4 alo = *(const float4*)&As[kk][ti * 8];
            float4 ahi = *(const float4*)&As[kk][ti * 8 + 4];
            float4 blo = *(const float4*)&Bs[kk][tj * 8];
            float4 bhi = *(const float4*)&Bs[kk][tj * 8 + 4];
            float av[8] = {alo.x, alo.y, alo.z, alo.w, ahi.x, ahi.y, ahi.z, ahi.w};
            float bv[8] = {blo.x, blo.y, blo.z, blo.w, bhi.x, bhi.y, bhi.z, bhi.w};
#pragma unroll
            for (int i = 0; i < 8; ++i)
#pragma unroll
                for (int j = 0; j < 8; ++j)
                    acc[i][j] = fmaf(av[i], bv[j], acc[i][j]);
        }
        __syncthreads();
    }

    float* Gb = G + (size_t)bat * CDIM * CDIM;
#pragma unroll
    for (int i = 0; i < 8; ++i) {
        const int row = bi * 128 + ti * 8 + i;
        float* gr = Gb + (size_t)row * CDIM + bj * 128 + tj * 8;
        *(float4*)(gr)     = make_float4(acc[i][0], acc[i][1], acc[i][2], acc[i][3]);
        *(float4*)(gr + 4) = make_float4(acc[i][4], acc[i][5], acc[i][6], acc[i][7]);
    }
}

// ---------------------------------------------------------------------------
// Kernel 3: scatter Gram into 8192 bins + signed sqrt + L2 normalize.
// One workgroup per batch. bins in LDS; h/s tables in LDS.
// y[b,k] = sum_{c1,c2 : (h1[c1]+h2[c2]) mod P == k} s1[c1]*s2[c2]*G[b,c1,c2]
// ---------------------------------------------------------------------------
__global__ __launch_bounds__(256) void scatter_kernel(
    const float* __restrict__ G,
    const int* __restrict__ h1, const float* __restrict__ s1,
    const int* __restrict__ h2, const float* __restrict__ s2,
    float* __restrict__ out)
{
    const int bat = blockIdx.x;
    __shared__ float bins[PROJ];          // 32 KB
    __shared__ int   sh1[CDIM];
    __shared__ float ss1[CDIM];
    __shared__ int   sh2[CDIM];
    __shared__ float ss2[CDIM];
    __shared__ float wred[4];

    const int tid = threadIdx.x;
    for (int i = tid; i < PROJ; i += 256) bins[i] = 0.0f;
    for (int i = tid; i < CDIM; i += 256) {
        sh1[i] = h1[i]; ss1[i] = s1[i];
        sh2[i] = h2[i]; ss2[i] = s2[i];
    }
    __syncthreads();

    const float* Gb = G + (size_t)bat * CDIM * CDIM;

    // 262144 pairs; thread reads float4 of G (4 consecutive c2), 256 iters.
    for (int it = 0; it < 256; ++it) {
        const int p  = it * 1024 + tid * 4;   // pair index, 16B aligned
        const int c1 = p >> 9;
        const int c2 = p & 511;
        float4 g = *(const float4*)(Gb + p);
        const int   base = sh1[c1];
        const float sg1  = ss1[c1];
        atomicAdd(&bins[(base + sh2[c2 + 0]) & (PROJ - 1)], sg1 * ss2[c2 + 0] * g.x);
        atomicAdd(&bins[(base + sh2[c2 + 1]) & (PROJ - 1)], sg1 * ss2[c2 + 1] * g.y);
        atomicAdd(&bins[(base + sh2[c2 + 2]) & (PROJ - 1)], sg1 * ss2[c2 + 2] * g.z);
        atomicAdd(&bins[(base + sh2[c2 + 3]) & (PROJ - 1)], sg1 * ss2[c2 + 3] * g.w);
    }
    __syncthreads();

    // epilogue: y = sign(v)*sqrt(|v|); note y^2 == |v| (exact up to rounding)
    float local = 0.0f;
    for (int i = tid; i < PROJ; i += 256) local += fabsf(bins[i]);
#pragma unroll
    for (int off = 32; off > 0; off >>= 1) local += __shfl_down(local, off, 64);
    if ((tid & 63) == 0) wred[tid >> 6] = local;
    __syncthreads();
    const float total = wred[0] + wred[1] + wred[2] + wred[3];
    const float inv   = rsqrtf(fmaxf(total, 1e-10f));

    float* ob = out + (size_t)bat * PROJ;
    for (int i = tid; i < PROJ; i += 256) {
        const float v  = bins[i];
        const float sv = (v >= 0.0f) ? sqrtf(v) : -sqrtf(-v);
        ob[i] = sv * inv;
    }
}

// ---------------------------------------------------------------------------
extern "C" void kernel_launch(void* const* d_in, const int* in_sizes, int n_in,
                              void* d_out, int out_size, void* d_ws, size_t ws_size,
                              hipStream_t stream)
{
    const float* x  = (const float*)d_in[0];   // [32,14,14,512]
    const float* M1 = (const float*)d_in[1];   // [512,8192]
    const float* M2 = (const float*)d_in[2];   // [512,8192]
    float* out = (float*)d_out;                // [32,8192]

    char* ws = (char*)d_ws;
    int*   h1 = (int*)  (ws + 0);
    float* s1 = (float*)(ws + 2048);
    int*   h2 = (int*)  (ws + 4096);
    float* s2 = (float*)(ws + 6144);
    float* G  = (float*)(ws + 8192);           // 32*512*512*4 = 33.5 MB

    extract_kernel<<<dim3(512, 2), 256, 0, stream>>>(M1, M2, h1, s1, h2, s2);
    gram_kernel<<<dim3(4, 4, NBATCH), 256, 0, stream>>>(x, G);
    scatter_kernel<<<NBATCH, 256, 0, stream>>>(G, h1, s1, h2, s2, out);
}

// Round 2
// 187.616 us; speedup vs baseline: 2.4928x; 2.4928x over previous
//
#include <hip/hip_runtime.h>
#include <math.h>

#define PROJ 8192
#define CDIM 512
#define HWPOS 196
#define NBATCH 32
#define SPLITS 32            // c1 splits for the scatter phase
#define ROWS_PER_SPLIT (CDIM / SPLITS)   // 16 rows -> 8192 pairs -> 32 KB of G

// ---------------------------------------------------------------------------
// Kernel 1: extract (h, s) from the dense sketch matrices + zero norm accum.
// Each row of M [512 x 8192] has exactly one nonzero (+-1) at column h[c].
// Grid: (512 rows, 2 matrices), block 256.
// ---------------------------------------------------------------------------
__global__ __launch_bounds__(256) void extract_kernel(
    const float* __restrict__ M1, const float* __restrict__ M2,
    int* __restrict__ h1, float* __restrict__ s1,
    int* __restrict__ h2, float* __restrict__ s2,
    float* __restrict__ norm)
{
    const int row = blockIdx.x;
    const float* M = blockIdx.y ? M2 : M1;
    int*   h = blockIdx.y ? h2 : h1;
    float* s = blockIdx.y ? s2 : s1;
    const float* mrow = M + (size_t)row * PROJ;

    if (blockIdx.x == 0 && blockIdx.y == 0 && threadIdx.x < NBATCH)
        norm[threadIdx.x] = 0.0f;                  // ws is poisoned each call

    // 256 threads x 8 float4 = 8192 elements
    for (int i = threadIdx.x * 4; i < PROJ; i += 256 * 4) {
        float4 v = *(const float4*)(mrow + i);
        if (v.x != 0.0f) { h[row] = i + 0; s[row] = v.x; }
        if (v.y != 0.0f) { h[row] = i + 1; s[row] = v.y; }
        if (v.z != 0.0f) { h[row] = i + 2; s[row] = v.z; }
        if (v.w != 0.0f) { h[row] = i + 3; s[row] = v.w; }
    }
}

// ---------------------------------------------------------------------------
// Kernel 2: batched Gram  G[b] = X_b^T X_b,  X_b = x[b] reshaped [196 x 512].
// Tile 128x128 of G per workgroup, 256 threads, 8x8 per-thread register block.
// Grid: (4, 4, 32).
// ---------------------------------------------------------------------------
__global__ __launch_bounds__(256) void gram_kernel(
    const float* __restrict__ x, float* __restrict__ G)
{
    const int bat = blockIdx.z;
    const int bi  = blockIdx.x;   // row tile of G (c1 / 128)
    const int bj  = blockIdx.y;   // col tile of G (c2 / 128)

    __shared__ __align__(16) float As[8][128];
    __shared__ __align__(16) float Bs[8][128];

    const float* Xb = x + (size_t)bat * HWPOS * CDIM;

    float acc[8][8];
#pragma unroll
    for (int i = 0; i < 8; ++i)
#pragma unroll
        for (int j = 0; j < 8; ++j) acc[i][j] = 0.0f;

    const int tid  = threadIdx.x;
    const int ti   = tid >> 4;        // 0..15 (G sub-row group)
    const int tj   = tid & 15;        // 0..15 (G sub-col group)
    const int lrow = tid >> 5;        // 0..7  (staging row)
    const int lcol = (tid & 31) * 4;  // 0..124 (staging col, float4)

    for (int k0 = 0; k0 < HWPOS; k0 += 8) {
        const int krow = k0 + lrow;
        float4 a4 = make_float4(0.f, 0.f, 0.f, 0.f);
        float4 b4 = make_float4(0.f, 0.f, 0.f, 0.f);
        if (krow < HWPOS) {
            const float* xr = Xb + (size_t)krow * CDIM;
            a4 = *(const float4*)(xr + bi * 128 + lcol);
            b4 = *(const float4*)(xr + bj * 128 + lcol);
        }
        *(float4*)&As[lrow][lcol] = a4;
        *(float4*)&Bs[lrow][lcol] = b4;
        __syncthreads();

#pragma unroll
        for (int kk = 0; kk < 8; ++kk) {
            float4 alo = *(const float4*)&As[kk][ti * 8];
            float4 ahi = *(const float4*)&As[kk][ti * 8 + 4];
            float4 blo = *(const float4*)&Bs[kk][tj * 8];
            float4 bhi = *(const float4*)&Bs[kk][tj * 8 + 4];
            float av[8] = {alo.x, alo.y, alo.z, alo.w, ahi.x, ahi.y, ahi.z, ahi.w};
            float bv[8] = {blo.x, blo.y, blo.z, blo.w, bhi.x, bhi.y, bhi.z, bhi.w};
#pragma unroll
            for (int i = 0; i < 8; ++i)
#pragma unroll
                for (int j = 0; j < 8; ++j)
                    acc[i][j] = fmaf(av[i], bv[j], acc[i][j]);
        }
        __syncthreads();
    }

    float* Gb = G + (size_t)bat * CDIM * CDIM;
#pragma unroll
    for (int i = 0; i < 8; ++i) {
        const int row = bi * 128 + ti * 8 + i;
        float* gr = Gb + (size_t)row * CDIM + bj * 128 + tj * 8;
        *(float4*)(gr)     = make_float4(acc[i][0], acc[i][1], acc[i][2], acc[i][3]);
        *(float4*)(gr + 4) = make_float4(acc[i][4], acc[i][5], acc[i][6], acc[i][7]);
    }
}

// ---------------------------------------------------------------------------
// Kernel 3: partial scatter. Grid (SPLITS, NBATCH), 256 threads.
// WG (s,b) owns G[b] rows [s*16, s*16+16) == contiguous 32 KB == 8192 pairs.
// Scatters them into LDS bins[8192], then writes the partial bins back OVER
// the same 32 KB of G it consumed (read-set == write-set, fenced by barrier).
// ---------------------------------------------------------------------------
__global__ __launch_bounds__(256) void scatter_partial_kernel(
    float* __restrict__ G,
    const int* __restrict__ h1, const float* __restrict__ s1,
    const int* __restrict__ h2, const float* __restrict__ s2)
{
    const int spl = blockIdx.x;
    const int bat = blockIdx.y;
    const int tid = threadIdx.x;

    __shared__ float bins[PROJ];       // 32 KB
    __shared__ int   sh1[ROWS_PER_SPLIT];
    __shared__ float ss1[ROWS_PER_SPLIT];
    __shared__ int   sh2[CDIM];
    __shared__ float ss2[CDIM];

    for (int i = tid; i < PROJ; i += 256) bins[i] = 0.0f;
    if (tid < ROWS_PER_SPLIT) {
        sh1[tid] = h1[spl * ROWS_PER_SPLIT + tid];
        ss1[tid] = s1[spl * ROWS_PER_SPLIT + tid];
    }
    for (int i = tid; i < CDIM; i += 256) { sh2[i] = h2[i]; ss2[i] = s2[i]; }
    __syncthreads();

    float* Gblk = G + (size_t)bat * CDIM * CDIM + (size_t)spl * ROWS_PER_SPLIT * CDIM;

    // 8192 pairs; thread reads 8 float4 (4 consecutive c2 each).
#pragma unroll
    for (int it = 0; it < 8; ++it) {
        const int p   = it * 1024 + tid * 4;  // local pair idx in [0, 8192)
        const int c1l = p >> 9;
        const int c2  = p & 511;
        float4 g = *(const float4*)(Gblk + p);
        const int   base = sh1[c1l];
        const float sg1  = ss1[c1l];
        atomicAdd(&bins[(base + sh2[c2 + 0]) & (PROJ - 1)], sg1 * ss2[c2 + 0] * g.x);
        atomicAdd(&bins[(base + sh2[c2 + 1]) & (PROJ - 1)], sg1 * ss2[c2 + 1] * g.y);
        atomicAdd(&bins[(base + sh2[c2 + 2]) & (PROJ - 1)], sg1 * ss2[c2 + 2] * g.z);
        atomicAdd(&bins[(base + sh2[c2 + 3]) & (PROJ - 1)], sg1 * ss2[c2 + 3] * g.w);
    }
    __syncthreads();   // all G reads done; safe to overwrite with partials

#pragma unroll
    for (int it = 0; it < 8; ++it) {
        const int i = it * 1024 + tid * 4;
        *(float4*)(Gblk + i) = *(const float4*)&bins[i];
    }
}

// ---------------------------------------------------------------------------
// Kernel 4: reduce 32 partials per bin, signed sqrt, emit unnormalized y,
// accumulate per-batch sum of |v| (== sum of y^2). Grid (8 chunks, 32 batches).
// ---------------------------------------------------------------------------
__global__ __launch_bounds__(256) void reduce_kernel(
    const float* __restrict__ G, float* __restrict__ out,
    float* __restrict__ norm)
{
    const int chunk = blockIdx.x;       // 0..7 : 1024 bins each
    const int bat   = blockIdx.y;
    const int tid   = threadIdx.x;
    const int base  = chunk * 1024 + tid * 4;

    const float* Gb = G + (size_t)bat * CDIM * CDIM;

    float4 v = make_float4(0.f, 0.f, 0.f, 0.f);
#pragma unroll
    for (int s = 0; s < SPLITS; ++s) {
        float4 p = *(const float4*)(Gb + (size_t)s * PROJ + base);
        v.x += p.x; v.y += p.y; v.z += p.z; v.w += p.w;
    }

    float4 sv;
    sv.x = (v.x >= 0.f) ? sqrtf(v.x) : -sqrtf(-v.x);
    sv.y = (v.y >= 0.f) ? sqrtf(v.y) : -sqrtf(-v.y);
    sv.z = (v.z >= 0.f) ? sqrtf(v.z) : -sqrtf(-v.z);
    sv.w = (v.w >= 0.f) ? sqrtf(v.w) : -sqrtf(-v.w);
    *(float4*)(out + (size_t)bat * PROJ + base) = sv;

    float local = fabsf(v.x) + fabsf(v.y) + fabsf(v.z) + fabsf(v.w);
#pragma unroll
    for (int off = 32; off > 0; off >>= 1) local += __shfl_down(local, off, 64);

    __shared__ float wred[4];
    if ((tid & 63) == 0) wred[tid >> 6] = local;
    __syncthreads();
    if (tid == 0)
        atomicAdd(&norm[bat], wred[0] + wred[1] + wred[2] + wred[3]);
}

// ---------------------------------------------------------------------------
// Kernel 5: scale by rsqrt(norm). Grid (8, 32), one float4 per thread.
// ---------------------------------------------------------------------------
__global__ __launch_bounds__(256) void normalize_kernel(
    float* __restrict__ out, const float* __restrict__ norm)
{
    const int bat = blockIdx.y;
    const int idx = blockIdx.x * 1024 + threadIdx.x * 4;
    const float inv = rsqrtf(fmaxf(norm[bat], 1e-10f));
    float4* p = (float4*)(out + (size_t)bat * PROJ + idx);
    float4 v = *p;
    v.x *= inv; v.y *= inv; v.z *= inv; v.w *= inv;
    *p = v;
}

// ---------------------------------------------------------------------------
extern "C" void kernel_launch(void* const* d_in, const int* in_sizes, int n_in,
                              void* d_out, int out_size, void* d_ws, size_t ws_size,
                              hipStream_t stream)
{
    const float* x  = (const float*)d_in[0];   // [32,14,14,512]
    const float* M1 = (const float*)d_in[1];   // [512,8192]
    const float* M2 = (const float*)d_in[2];   // [512,8192]
    float* out = (float*)d_out;                // [32,8192]

    char* ws = (char*)d_ws;
    int*   h1   = (int*)  (ws + 0);
    float* s1   = (float*)(ws + 2048);
    int*   h2   = (int*)  (ws + 4096);
    float* s2   = (float*)(ws + 6144);
    float* norm = (float*)(ws + 8192);         // 32 floats
    float* G    = (float*)(ws + 16384);        // 32*512*512*4 = 33.5 MB

    extract_kernel<<<dim3(512, 2), 256, 0, stream>>>(M1, M2, h1, s1, h2, s2, norm);
    gram_kernel<<<dim3(4, 4, NBATCH), 256, 0, stream>>>(x, G);
    scatter_partial_kernel<<<dim3(SPLITS, NBATCH), 256, 0, stream>>>(G, h1, s1, h2, s2);
    reduce_kernel<<<dim3(8, NBATCH), 256, 0, stream>>>(G, out, norm);
    normalize_kernel<<<dim3(8, NBATCH), 256, 0, stream>>>(out, norm);
}